// Round 4
// baseline (241.313 us; speedup 1.0000x reference)
//
#include <hip/hip_runtime.h>

// AccumulatorLIF: I[t] = exp(-1/2)*I[t-1] + x[t]; out = sigmoid(4*(I-0.5))
// x: (T=1024, B=32, F=1024) fp32. ~268 MB ideal HBM traffic -> memory-bound.
//
// R8 (single-variable vs R6): LCHUNK 16->32, KHALO stays 16. Loads/output
// 2.0 -> 1.5; through-cache read bytes 201 -> 168 MB. R7 exonerated the
// store path (nt vs plain neutral after fill-rate normalization; nt
// restored here). Latency/VALU/issue all have >10x margin by arithmetic,
// so warm-read amplification is the last structural suspect before the
// exact two-pass carry decomposition.
//
// Carried: all loads that feed a compute group are issued BEFORE the
// stores that precede that group in the in-order vmcnt FIFO (a/b buffer
// rotation); KHALO=16 (trunc err d^16*7 ~ 2.3e-3 << 2e-2); ~80 VGPR,
// launch_bounds(256,6). Grid: NCHUNK=32 chunks x 32 blocks = 1024 blocks
// -> 4 blocks/CU = 16 waves/CU (MLP margin still ~16x).

#define T_DIM   1024
#define B_DIM   32
#define F_DIM   1024
#define LCHUNK  32
#define KHALO   16
#define F4_DIM  (F_DIM / 4)          // 256 float4 per (t,b) row
#define SEQ4    (B_DIM * F4_DIM)     // 8192 float4 per time step
#define NCHUNK  (T_DIM / LCHUNK)     // 32
#define G       8

typedef float f32x4 __attribute__((ext_vector_type(4)));

__device__ __forceinline__ float spike1(float I) {
    // sigmoid(4*(I-0.5)) = 1 / (1 + exp(-4*(I-0.5)))
    float z = fmaf(-4.0f, I, 2.0f);
    float e = __expf(z);
    return __builtin_amdgcn_rcpf(1.0f + e);
}

__device__ __forceinline__ f32x4 spike4(f32x4 I) {
    f32x4 r;
    r.x = spike1(I.x); r.y = spike1(I.y); r.z = spike1(I.z); r.w = spike1(I.w);
    return r;
}

__device__ __forceinline__ void load8(const f32x4* __restrict__ x,
                                      f32x4 (&buf)[G], int base) {
    #pragma unroll
    for (int j = 0; j < G; ++j) buf[j] = x[base + j * SEQ4];
}

__device__ __forceinline__ void fma8(f32x4 (&buf)[G], f32x4& I, float d) {
    #pragma unroll
    for (int j = 0; j < G; ++j) I = d * I + buf[j];
}

__device__ __forceinline__ void fmastore8(f32x4 (&buf)[G], f32x4& I, float d,
                                          f32x4* __restrict__ out, int base) {
    #pragma unroll
    for (int j = 0; j < G; ++j) {
        I = d * I + buf[j];
        __builtin_nontemporal_store(spike4(I), &out[base + j * SEQ4]);
    }
}

__global__ __launch_bounds__(256, 6) void lif_scan_kernel(
        const f32x4* __restrict__ x, f32x4* __restrict__ out) {
    const float d = 0.60653065971263342f;     // exp(-0.5)

    int tid   = blockIdx.x * 256 + threadIdx.x;
    int s     = tid & (SEQ4 - 1);             // float4 index within time slice
    int chunk = tid >> 13;                    // block-uniform (32 blocks/chunk)
    int t0    = chunk * LCHUNK;

    f32x4 I = (f32x4)(0.0f);
    f32x4 a[G], b[G];
    const int GS = G * SEQ4;

    if (t0 == 0) {
        // Chunk 0: no halo. 4 main groups, a/b rotation; every compute
        // group's loads are issued before the stores that precede them.
        int li = s;
        load8(x, a, li); li += GS;
        load8(x, b, li); li += GS;
        int si = s;
        fmastore8(a, I, d, out, si);          // g0
        load8(x, a, li); li += GS;            // g2 loads
        fmastore8(b, I, d, out, si + GS);     // g1
        load8(x, b, li);                      // g3 loads
        fmastore8(a, I, d, out, si + 2 * GS); // g2
        fmastore8(b, I, d, out, si + 3 * GS); // g3
    } else {
        // 16 halo steps (accumulate only) + 32 main steps, pipelined.
        int li = (t0 - KHALO) * SEQ4 + s;     // t0 >= 32 -> always >= 0
        load8(x, a, li); li += GS;            // warm0 loads
        load8(x, b, li); li += GS;            // warm1 loads
        fma8(a, I, d);                        // warm0
        load8(x, a, li); li += GS;            // m0 loads
        fma8(b, I, d);                        // warm1
        load8(x, b, li); li += GS;            // m1 loads

        int si = t0 * SEQ4 + s;
        fmastore8(a, I, d, out, si);          // m0
        load8(x, a, li); li += GS;            // m2 loads
        fmastore8(b, I, d, out, si + GS);     // m1
        load8(x, b, li);                      // m3 loads
        fmastore8(a, I, d, out, si + 2 * GS); // m2
        fmastore8(b, I, d, out, si + 3 * GS); // m3
    }
}

extern "C" void kernel_launch(void* const* d_in, const int* in_sizes, int n_in,
                              void* d_out, int out_size, void* d_ws, size_t ws_size,
                              hipStream_t stream) {
    const f32x4* x   = (const f32x4*)d_in[0];
    f32x4*       out = (f32x4*)d_out;
    int total_threads = NCHUNK * SEQ4;        // 262144
    dim3 grid(total_threads / 256), block(256);
    lif_scan_kernel<<<grid, block, 0, stream>>>(x, out);
}